// Round 4
// baseline (247.068 us; speedup 1.0000x reference)
//
#include <hip/hip_runtime.h>
#include <hip/hip_bf16.h>
#include <math.h>

#define Bn 64
#define Tn 256
#define Cn 384
#define Hn 6
#define HSn 64
#define FFn 1536
#define EPSn 1e-3f
#define SECn 6291456  // B*H*T*HS = one q/k/v section, elements

typedef __attribute__((ext_vector_type(4))) float f32x4;
typedef __attribute__((ext_vector_type(2))) float f32x2;
typedef __attribute__((ext_vector_type(8))) short short8;
typedef __attribute__((ext_vector_type(4))) short short4v;
typedef __attribute__((ext_vector_type(2))) short short2v;

__device__ __forceinline__ void async_copy16(void* lds, const void* g) {
    __builtin_amdgcn_global_load_lds(
        (const __attribute__((address_space(1))) void*)g,
        (__attribute__((address_space(3))) void*)lds, 16, 0, 0);
}

__device__ __forceinline__ short f2bf(float v) {
    __hip_bfloat16 h = __float2bfloat16(v);
    return *(short*)&h;
}

// Packed-A layout for [M x K] bf16: fragment block (mt, kc) of 1 KB:
//   addr = ((mt * (K/32) + kc) * 512) + lane*8 + j
//   value = A[mt*16 + (lane&15)][kc*32 + (lane>>4)*8 + j]

// ---------------- LayerNorm -> packed-A bf16 (block = 16 rows = one m-tile) ----------------
__global__ __launch_bounds__(256) void ln_pack_kernel(const float* __restrict__ x,
                                                      const float* __restrict__ g,
                                                      const float* __restrict__ be,
                                                      __hip_bfloat16* __restrict__ outPk) {
    int mt = blockIdx.x;
    int tid = threadIdx.x;
    int lane = tid & 63, wave = tid >> 6;
    __shared__ short rows[16 * 392];  // stride 392 shorts (784 B, 16B-aligned per row)
#pragma unroll
    for (int i = 0; i < 4; i++) {
        int r = wave * 4 + i;
        const float* xr = x + ((size_t)mt * 16 + r) * Cn;
        f32x4 a = *(const f32x4*)(xr + lane * 4);
        f32x2 b = *(const f32x2*)(xr + 256 + lane * 2);
        float s = a.x + a.y + a.z + a.w + b.x + b.y;
#pragma unroll
        for (int off = 32; off; off >>= 1) s += __shfl_xor(s, off);
        float mu = s * (1.0f / Cn);
        f32x4 da = a - mu;
        f32x2 db = b - mu;
        float sq = da.x * da.x + da.y * da.y + da.z * da.z + da.w * da.w + db.x * db.x + db.y * db.y;
#pragma unroll
        for (int off = 32; off; off >>= 1) sq += __shfl_xor(sq, off);
        float rs = rsqrtf(sq * (1.0f / Cn) + EPSn);
        f32x4 g4 = *(const f32x4*)(g + lane * 4);
        f32x2 g2 = *(const f32x2*)(g + 256 + lane * 2);
        f32x4 e4 = *(const f32x4*)(be + lane * 4);
        f32x2 e2 = *(const f32x2*)(be + 256 + lane * 2);
        f32x4 y4 = da * rs * g4 + e4;
        f32x2 y2 = db * rs * g2 + e2;
        short4v o4 = {f2bf(y4.x), f2bf(y4.y), f2bf(y4.z), f2bf(y4.w)};
        *(short4v*)(&rows[r * 392 + lane * 4]) = o4;
        short2v o2 = {f2bf(y2.x), f2bf(y2.y)};
        *(short2v*)(&rows[r * 392 + 256 + lane * 2]) = o2;
    }
    __syncthreads();
    int r = lane & 15, q = lane >> 4;
#pragma unroll
    for (int p = 0; p < 3; p++) {
        int f = p * 4 + (tid >> 6);  // fragment (k-chunk) 0..11
        short8 v = *(const short8*)(&rows[r * 392 + f * 32 + q * 8]);
        *(short8*)((short*)outPk + ((size_t)mt * 12 + f) * 512 + lane * 8) = v;
    }
}

// ---------------- Pack a [K,N] row-major fp32 weight into MFMA B-fragment order ----------------
__global__ __launch_bounds__(256) void pack_b_kernel(const float* __restrict__ W,
                                                     __hip_bfloat16* __restrict__ out,
                                                     int K, int N) {
    int id = blockIdx.x * 256 + threadIdx.x;
    if (id >= K * N) return;
    int tile = id >> 9, lane = (id >> 3) & 63, j = id & 7;
    int ntiles = N >> 4;
    int k = (tile / ntiles) * 32 + ((lane >> 4) << 3) + j;
    int n = (tile % ntiles) * 16 + (lane & 15);
    out[id] = __float2bfloat16(W[(size_t)k * N + n]);
}

// ---------------- Pack fused [Wq|Wk|Wv] into one B [K=384, N=1152] ----------------
__global__ __launch_bounds__(256) void pack_qkv_kernel(const float* __restrict__ Wq,
                                                       const float* __restrict__ Wk,
                                                       const float* __restrict__ Wv,
                                                       __hip_bfloat16* __restrict__ out) {
    int id = blockIdx.x * 256 + threadIdx.x;
    if (id >= Cn * 1152) return;
    int tile = id >> 9, lane = (id >> 3) & 63, j = id & 7;
    int k = (tile / 72) * 32 + ((lane >> 4) << 3) + j;
    int n = (tile % 72) * 16 + (lane & 15);
    int sec = n / Cn, rem = n % Cn;
    int hh = rem >> 6, d = rem & 63;
    const float* W = (sec == 0) ? Wq : ((sec == 1) ? Wk : Wv);
    out[id] = __float2bfloat16(W[((size_t)hh * Cn + k) * HSn + d]);
}

// ---------------- Persistent-B MFMA GEMM for K=384: whole B panel in LDS ----------------
// Block tile 128(M) x 64(N). The ENTIRE B panel for this colblk (K=384 x 64 = 48 KB,
// 48 fragment tiles) is staged ONCE into LDS via global_load_lds; one barrier; then a
// fully barrier-free K-loop: A fragment-direct from global in 4 quarter-K register
// double-buffers (static indices), B via conflict-free ds_read_b128 (lane*16B).
// No per-chunk vmcnt drains (the m97-ceiling stall) - the 96 MFMAs/wave run straight
// through. Epilogue reuses the then-dead B panel as transpose strips (one barrier).
// LDS = 48 KB -> 3 blocks/CU.
template <int NN, int EPI>
__global__ __launch_bounds__(256, 3) void gemm_persist(const __hip_bfloat16* __restrict__ Apk,
                                                       const __hip_bfloat16* __restrict__ Bp,
                                                       const float* __restrict__ bias,
                                                       const float* __restrict__ resid,
                                                       float* __restrict__ outF,
                                                       __hip_bfloat16* __restrict__ outB) {
    constexpr int GX = NN / 64;
    constexpr int K32 = 12;  // K = 384
    constexpr int NT16 = NN / 16;
    __shared__ __align__(16) short ldsB[48 * 512];  // 48 KB: full B panel; then epi strips

    int l = blockIdx.x;
    int xcd = l & 7, i = l >> 3;
    int rowblk = xcd * 16 + i / GX;
    int colblk = i - (i / GX) * GX;

    int lane = threadIdx.x & 63, wave = threadIdx.x >> 6;
    int lrow = lane & 15, lquad = lane >> 4;
    int m0 = rowblk * 128;
    int n0 = colblk * 64;
    int mt0 = (m0 >> 4) + wave * 2;  // wave's two m-tiles: mt0, mt0+1

    // stage full B panel: 48 tiles of 1 KB, 12 per wave
    {
        const short* bbase = (const short*)Bp + (size_t)(n0 >> 4) * 512 + lane * 8;
#pragma unroll
        for (int t = 0; t < 12; t++) {
            int idx = wave * 12 + t;       // tile index = kf*4 + ntl
            int kf = idx >> 2, ntl = idx & 3;
            async_copy16(&ldsB[idx * 512], bbase + ((size_t)kf * NT16 + ntl) * 512);
        }
    }

    f32x4 acc[2][4];
#pragma unroll
    for (int st = 0; st < 2; st++)
#pragma unroll
        for (int nt = 0; nt < 4; nt++) acc[st][nt] = (f32x4){0.f, 0.f, 0.f, 0.f};

    const short* a0p = (const short*)Apk + ((size_t)mt0 * K32) * 512 + lane * 8;
    const short* a1p = a0p + (size_t)K32 * 512;

    // A quarter-K register double buffer: 3 kf per quarter, 4 quarters
    short8 af[2][2][3];
#pragma unroll
    for (int kf = 0; kf < 3; kf++) {
        af[0][0][kf] = *(const short8*)(a0p + kf * 512);
        af[0][1][kf] = *(const short8*)(a1p + kf * 512);
    }
    __syncthreads();  // B panel ready

#pragma unroll
    for (int q = 0; q < 4; q++) {
        if (q < 3) {
#pragma unroll
            for (int kf = 0; kf < 3; kf++) {
                af[(q + 1) & 1][0][kf] = *(const short8*)(a0p + ((q + 1) * 3 + kf) * 512);
                af[(q + 1) & 1][1][kf] = *(const short8*)(a1p + ((q + 1) * 3 + kf) * 512);
            }
        }
#pragma unroll
        for (int kf = 0; kf < 3; kf++) {
            int kfa = q * 3 + kf;
#pragma unroll
            for (int nt = 0; nt < 4; nt++) {
                short8 bf = *(const short8*)(&ldsB[(kfa * 4 + nt) * 512 + lane * 8]);
                acc[0][nt] = __builtin_amdgcn_mfma_f32_16x16x32_bf16(af[q & 1][0][kf], bf,
                                                                     acc[0][nt], 0, 0, 0);
                acc[1][nt] = __builtin_amdgcn_mfma_f32_16x16x32_bf16(af[q & 1][1][kf], bf,
                                                                     acc[1][nt], 0, 0, 0);
            }
        }
    }
    __syncthreads();  // B panel dead -> reuse as epilogue strips

    if (EPI == 1) {
        // fp32 out = resid + acc + bias (row-major), strip-by-strip (16 x 64 fp32, stride 76)
        float* twf = (float*)((char*)ldsB + wave * 4864);
        float bnv[4];
#pragma unroll
        for (int nt = 0; nt < 4; nt++) bnv[nt] = bias[n0 + nt * 16 + lrow];
#pragma unroll
        for (int st = 0; st < 2; st++) {
            int mbase = m0 + (2 * wave + st) * 16;
#pragma unroll
            for (int nt = 0; nt < 4; nt++)
#pragma unroll
                for (int r = 0; r < 4; r++)
                    twf[(lquad * 4 + r) * 76 + nt * 16 + lrow] = acc[st][nt][r] + bnv[nt];
            int row = lane >> 2, seg = lane & 3;
            int m = mbase + row;
            const float* rrow = resid + (size_t)m * NN + n0 + seg * 16;
            float* orow = outF + (size_t)m * NN + n0 + seg * 16;
#pragma unroll
            for (int c = 0; c < 4; c++) {
                f32x4 vv = *(const f32x4*)(&twf[row * 76 + seg * 16 + c * 4]);
                f32x4 rv = *(const f32x4*)(rrow + c * 4);
                *(f32x4*)(orow + c * 4) = vv + rv;
            }
            __builtin_amdgcn_s_waitcnt(0);  // wave-local strip reuse
        }
    } else {
        // bf16 cases: full 32 rows x 64 cols per-wave strip (stride 72 shorts, 16B-aligned rows)
        short* tws = (short*)((char*)ldsB + wave * 4864);
        float bnv[4];
        if (EPI == 2) {
#pragma unroll
            for (int nt = 0; nt < 4; nt++) bnv[nt] = bias[n0 + nt * 16 + lrow];
        }
#pragma unroll
        for (int st = 0; st < 2; st++)
#pragma unroll
            for (int nt = 0; nt < 4; nt++)
#pragma unroll
                for (int r = 0; r < 4; r++) {
                    float v = acc[st][nt][r];
                    if (EPI == 2) v = fmaxf(v + bnv[nt], 0.0f);
                    tws[(st * 16 + lquad * 4 + r) * 72 + nt * 16 + lrow] = f2bf(v);
                }
        if (EPI == 2) {
            // y1 -> packed-A layout for FF2 (K_ff2 = NN, so K32_out = NN/32)
#pragma unroll
            for (int st2 = 0; st2 < 2; st2++) {
                int mt = (m0 >> 4) + wave * 2 + st2;
#pragma unroll
                for (int kcl = 0; kcl < 2; kcl++) {
                    int kc = (n0 >> 5) + kcl;
                    short8 v = *(const short8*)(
                        &tws[(st2 * 16 + (lane & 15)) * 72 + kcl * 32 + (lane >> 4) * 8]);
                    *(short8*)((short*)outB + ((size_t)mt * (NN / 32) + kc) * 512 + lane * 8) = v;
                }
            }
        } else {
            // EPI 0 (qkv): q -> packed-A frag tiles, k -> packed-B frag tiles (same mapping),
            // v -> packed-B frag tiles for PV. All fragment-direct, no row-major scatter.
            int sec = n0 / 384;
            int rem0 = n0 - sec * 384;
            int hh = rem0 >> 6;  // wave-uniform
            int b = m0 >> 8;
            int t_base = (m0 & 255) + wave * 32;
            int bh2 = b * Hn + hh;
            if (sec < 2) {
                // tile index (t/16)*2 + (d/32); value = X[t = st*16 + (lane&15)][d = kc*32 + quad*8 + j]
                short* outp = (short*)outB + (size_t)sec * SECn + (size_t)bh2 * 16384 +
                              (size_t)(t_base >> 4) * 1024 + lane * 8;
#pragma unroll
                for (int st2 = 0; st2 < 2; st2++)
#pragma unroll
                    for (int kc = 0; kc < 2; kc++) {
                        short8 v8 = *(const short8*)(
                            &tws[(st2 * 16 + (lane & 15)) * 72 + kc * 32 + (lane >> 4) * 8]);
                        *(short8*)(outp + (st2 * 2 + kc) * 512) = v8;
                    }
            } else {
                short* vout = (short*)outB + (size_t)2 * SECn + (size_t)bh2 * 16384 +
                              (size_t)((t_base >> 5) * 4) * 512;
#pragma unroll
                for (int dt = 0; dt < 4; dt++) {
                    short8 v8;
#pragma unroll
                    for (int j = 0; j < 8; j++) {
                        int t_loc = ((lane >> 4) << 3) + j;
                        v8[j] = tws[t_loc * 72 + dt * 16 + (lane & 15)];
                    }
                    *(short8*)(vout + dt * 512 + lane * 8) = v8;
                }
            }
        }
    }
}

// ---------------- Pipelined MFMA GEMM (K=1536 / FF2): LDS-shared B, chunked ----------------
template <int KK, int NN, int EPI>
__global__ __launch_bounds__(256) void gemm_mfma(const __hip_bfloat16* __restrict__ Apk,
                                                 const __hip_bfloat16* __restrict__ Bp,
                                                 const float* __restrict__ bias,
                                                 const float* __restrict__ resid,
                                                 float* __restrict__ outF,
                                                 __hip_bfloat16* __restrict__ outB) {
    constexpr int GX = NN / 64;
    constexpr int K32 = KK / 32;
    constexpr int NC = K32 / 4;   // number of 128-deep K chunks
    constexpr int NT16 = NN / 16;
    __shared__ __align__(16) short ldsB[2 * 8192];  // 32 KB: B chunk double buffer (+ epi strips)

    int l = blockIdx.x;
    int xcd = l & 7, i = l >> 3;
    int rowblk = xcd * 16 + i / GX;
    int colblk = i - (i / GX) * GX;

    int lane = threadIdx.x & 63, wave = threadIdx.x >> 6;
    int lrow = lane & 15, lquad = lane >> 4;
    int m0 = rowblk * 128;
    int n0 = colblk * 64;
    int mt0 = (m0 >> 4) + wave * 2;  // wave's two m-tiles: mt0, mt0+1

    f32x4 acc[2][4];
#pragma unroll
    for (int st = 0; st < 2; st++)
#pragma unroll
        for (int nt = 0; nt < 4; nt++) acc[st][nt] = (f32x4){0.f, 0.f, 0.f, 0.f};

    const short* a0p = (const short*)Apk + ((size_t)mt0 * K32) * 512 + lane * 8;
    const short* a1p = a0p + (size_t)K32 * 512;
    // B source for this wave's staged k-frag (kf == wave) of chunk 0:
    const short* bsrc = (const short*)Bp + ((size_t)wave * NT16 + (n0 >> 4)) * 512 + lane * 8;
    short* bdst0 = ldsB + wave * 2048;  // frags [kf=wave][nt 0..3]

    // prologue: stage chunk 0, load A chunk 0
#pragma unroll
    for (int nt = 0; nt < 4; nt++) async_copy16(bdst0 + nt * 512, bsrc + nt * 512);
    short8 aR[2][2][4];
#pragma unroll
    for (int kf = 0; kf < 4; kf++) {
        aR[0][0][kf] = *(const short8*)(a0p + kf * 512);
        aR[0][1][kf] = *(const short8*)(a1p + kf * 512);
    }

#pragma unroll
    for (int c = 0; c < NC; c++) {
        __syncthreads();  // B(c) ready (stage issued one full chunk ago)
        if (c + 1 < NC) {
            const short* bs = bsrc + (size_t)(c + 1) * 4 * NT16 * 512;
            short* bd = ldsB + ((c + 1) & 1) * 8192 + wave * 2048;
#pragma unroll
            for (int nt = 0; nt < 4; nt++) async_copy16(bd + nt * 512, bs + nt * 512);
#pragma unroll
            for (int kf = 0; kf < 4; kf++) {
                aR[(c + 1) & 1][0][kf] = *(const short8*)(a0p + ((c + 1) * 4 + kf) * 512);
                aR[(c + 1) & 1][1][kf] = *(const short8*)(a1p + ((c + 1) * 4 + kf) * 512);
            }
        }
        const short* bl = ldsB + (c & 1) * 8192 + lane * 8;
#pragma unroll
        for (int kf = 0; kf < 4; kf++) {
#pragma unroll
            for (int nt = 0; nt < 4; nt++) {
                short8 bf = *(const short8*)(bl + (kf * 4 + nt) * 512);
                acc[0][nt] = __builtin_amdgcn_mfma_f32_16x16x32_bf16(aR[c & 1][0][kf], bf,
                                                                     acc[0][nt], 0, 0, 0);
                acc[1][nt] = __builtin_amdgcn_mfma_f32_16x16x32_bf16(aR[c & 1][1][kf], bf,
                                                                     acc[1][nt], 0, 0, 0);
            }
        }
    }
    __syncthreads();  // before reusing ldsB as epilogue strips

    if (EPI == 1) {
        // fp32 out = resid + acc + bias (row-major), strip-by-strip (16 x 64 fp32, stride 76)
        float* twf = (float*)((char*)ldsB + wave * 4864);
        float bnv[4];
#pragma unroll
        for (int nt = 0; nt < 4; nt++) bnv[nt] = bias[n0 + nt * 16 + lrow];
#pragma unroll
        for (int st = 0; st < 2; st++) {
            int mbase = m0 + (2 * wave + st) * 16;
#pragma unroll
            for (int nt = 0; nt < 4; nt++)
#pragma unroll
                for (int r = 0; r < 4; r++)
                    twf[(lquad * 4 + r) * 76 + nt * 16 + lrow] = acc[st][nt][r] + bnv[nt];
            int row = lane >> 2, seg = lane & 3;
            int m = mbase + row;
            const float* rrow = resid + (size_t)m * NN + n0 + seg * 16;
            float* orow = outF + (size_t)m * NN + n0 + seg * 16;
#pragma unroll
            for (int c = 0; c < 4; c++) {
                f32x4 vv = *(const f32x4*)(&twf[row * 76 + seg * 16 + c * 4]);
                f32x4 rv = *(const f32x4*)(rrow + c * 4);
                *(f32x4*)(orow + c * 4) = vv + rv;
            }
            __builtin_amdgcn_s_waitcnt(0);  // wave-local strip reuse
        }
    } else {
        // bf16 cases (unused for FF2 but kept for completeness)
        short* tws = (short*)((char*)ldsB + wave * 4864);
        float bnv[4];
        if (EPI == 2) {
#pragma unroll
            for (int nt = 0; nt < 4; nt++) bnv[nt] = bias[n0 + nt * 16 + lrow];
        }
#pragma unroll
        for (int st = 0; st < 2; st++)
#pragma unroll
            for (int nt = 0; nt < 4; nt++)
#pragma unroll
                for (int r = 0; r < 4; r++) {
                    float v = acc[st][nt][r];
                    if (EPI == 2) v = fmaxf(v + bnv[nt], 0.0f);
                    tws[(st * 16 + lquad * 4 + r) * 72 + nt * 16 + lrow] = f2bf(v);
                }
        if (EPI == 2) {
#pragma unroll
            for (int st2 = 0; st2 < 2; st2++) {
                int mt = (m0 >> 4) + wave * 2 + st2;
#pragma unroll
                for (int kcl = 0; kcl < 2; kcl++) {
                    int kc = (n0 >> 5) + kcl;
                    short8 v = *(const short8*)(
                        &tws[(st2 * 16 + (lane & 15)) * 72 + kcl * 32 + (lane >> 4) * 8]);
                    *(short8*)((short*)outB + ((size_t)mt * (NN / 32) + kc) * 512 + lane * 8) = v;
                }
            }
        }
    }
}

// ---------------- Flash-style MFMA attention: K staged in LDS, split-PV ----------------
__global__ __launch_bounds__(256) void attn_mfma_kernel(const __hip_bfloat16* __restrict__ qp,
                                                        const __hip_bfloat16* __restrict__ kp,
                                                        const __hip_bfloat16* __restrict__ vp,
                                                        __hip_bfloat16* __restrict__ o) {
    __shared__ short Kl[16 * 1024];  // 32 KB: K fragment tiles, linear copy of kp section
    __shared__ short Pl[4 * 2048];   // 16 KB: per-wave P half-buffer (4 tiles) / epi strip
    int blk = blockIdx.x;
    int bh = blk % (Bn * Hn);  // jg-major: same-bh blocks land on the same XCD (384 % 8 == 0)
    int jg = blk / (Bn * Hn);
    int b = bh / Hn, hh = bh - b * Hn;
    int tid = threadIdx.x;
    int lane = tid & 63, wave = tid >> 6;
    int c16 = lane & 15, quad = lane >> 4;
    // zigzag q-tile assignment: every block's total causal work = 34 units
    int qt = (wave << 2) + ((wave & 1) ? (3 - jg) : jg);

    const short* ks = (const short*)kp + (size_t)bh * 16384;
    // stage all 32 K fragment tiles (1 KB each): 8 async copies per wave, LDS linear
#pragma unroll
    for (int i = 0; i < 8; i++) {
        int tile = wave * 8 + i;
        async_copy16(&Kl[tile * 512], ks + tile * 512 + lane * 8);
    }

    const short* qs = (const short*)qp + (size_t)bh * 16384 + (size_t)qt * 1024 + lane * 8;
    const short* vs = (const short*)vp + (size_t)bh * 16384 + lane * 8;
    short* Pw = Pl + wave * 2048;

    short8 aq0 = *(const short8*)(qs);
    short8 aq1 = *(const short8*)(qs + 512);

    int st_max = qt;
    int kb_count = (qt + 2) >> 1;
    int covered = kb_count * 2;
    int qrow0 = qt * 16;

    __syncthreads();  // K staged (compiler drains vmcnt before s_barrier)

    f32x4 accS[16];
#pragma unroll
    for (int st = 0; st < 16; st++) accS[st] = (f32x4){0.f, 0.f, 0.f, 0.f};
#pragma unroll
    for (int st = 0; st < 16; st++) {
        if (st <= st_max) {
            short8 bk0 = *(const short8*)(&Kl[st * 1024 + lane * 8]);
            short8 bk1 = *(const short8*)(&Kl[st * 1024 + 512 + lane * 8]);
            accS[st] = __builtin_amdgcn_mfma_f32_16x16x32_bf16(aq0, bk0, accS[st], 0, 0, 0);
            accS[st] = __builtin_amdgcn_mfma_f32_16x16x32_bf16(aq1, bk1, accS[st], 0, 0, 0);
        }
    }

    // pass 1: causal mask + scale + row max
    float mx[4];
#pragma unroll
    for (int r = 0; r < 4; r++) {
        int row = qrow0 + quad * 4 + r;
        float m = -INFINITY;
#pragma unroll
        for (int st = 0; st < 16; st++) {
            if (st <= st_max) {
                int col = st * 16 + c16;
                float a = (col <= row) ? accS[st][r] * 0.125f : -INFINITY;
                accS[st][r] = a;
                m = fmaxf(m, a);
            }
        }
#pragma unroll
        for (int off = 8; off; off >>= 1) m = fmaxf(m, __shfl_xor(m, off));
        mx[r] = m;
    }

    // pass 2: exp + P store + PV, in two 4-kbi halves (P half-buffer reuse)
    float sum[4] = {0.f, 0.f, 0.f, 0.f};
    f32x4 accO[4];
#pragma unroll
    for (int nt = 0; nt < 4; nt++) accO[nt] = (f32x4){0.f, 0.f, 0.f, 0.f};
#pragma unroll
    for (int half = 0; half < 2; half++) {
        int st_lo = half * 8;
        if (st_lo < covered) {
#pragma unroll
            for (int st2 = 0; st2 < 8; st2++) {
                int st = st_lo + st2;
                if (st < covered) {
#pragma unroll
                    for (int r = 0; r < 4; r++) {
                        float e = 0.0f;
                        if (st <= st_max) {
                            e = __expf(accS[st][r] - mx[r]);
                            sum[r] += e;
                        }
                        int cl = st2 * 16 + c16;
                        Pw[(cl >> 5) * 512 + (((cl >> 3) & 3) * 16 + quad * 4 + r) * 8 +
                           (cl & 7)] = f2bf(e);
                    }
                }
            }
#pragma unroll
            for (int k2 = 0; k2 < 4; k2++) {
                int kbi = half * 4 + k2;
                if (kbi < kb_count) {
                    short8 ap = *(const short8*)(Pw + k2 * 512 + lane * 8);
#pragma unroll
                    for (int nt = 0; nt < 4; nt++) {
                        short8 bv = *(const short8*)(vs + (kbi * 4 + nt) * 512);
                        accO[nt] = __builtin_amdgcn_mfma_f32_16x16x32_bf16(ap, bv, accO[nt],
                                                                           0, 0, 0);
                    }
                }
            }
        }
    }

    float inv[4];
#pragma unroll
    for (int r = 0; r < 4; r++) {
        float s = sum[r];
#pragma unroll
        for (int off = 8; off; off >>= 1) s += __shfl_xor(s, off);
        inv[r] = 1.0f / s;
    }

    // ---- O epilogue: C-layout -> strip (stride 72) -> packed-A global ----
#pragma unroll
    for (int nt = 0; nt < 4; nt++)
#pragma unroll
        for (int r = 0; r < 4; r++)
            Pw[(quad * 4 + r) * 72 + nt * 16 + c16] = f2bf(accO[nt][r] * inv[r]);
    int mt = (b << 4) + qt;  // (b*256 + qt*16) / 16
#pragma unroll
    for (int kcl = 0; kcl < 2; kcl++) {
        short8 v = *(const short8*)(&Pw[(lane & 15) * 72 + kcl * 32 + (lane >> 4) * 8]);
        *(short8*)((short*)o + ((size_t)mt * 12 + hh * 2 + kcl) * 512 + lane * 8) = v;
    }
}

extern "C" void kernel_launch(void* const* d_in, const int* in_sizes, int n_in,
                              void* d_out, int out_size, void* d_ws, size_t ws_size,
                              hipStream_t stream) {
    const float* x  = (const float*)d_in[0];
    const float* Wq = (const float*)d_in[1];
    const float* Wk = (const float*)d_in[2];
    const float* Wv = (const float*)d_in[3];
    const float* Wp = (const float*)d_in[4];
    const float* bp = (const float*)d_in[5];
    const float* W1 = (const float*)d_in[6];
    const float* b1 = (const float*)d_in[7];
    const float* W2 = (const float*)d_in[8];
    const float* b2 = (const float*)d_in[9];
    const float* g1 = (const float*)d_in[10];
    const float* be1 = (const float*)d_in[11];
    const float* g2 = (const float*)d_in[12];
    const float* be2 = (const float*)d_in[13];

    const size_t M = (size_t)Bn * Tn;  // 16384
    __hip_bfloat16* ws  = (__hip_bfloat16*)d_ws;
    __hip_bfloat16* h   = ws;               // M*384 bf16 packed-A (LN1 out; reused as h2)
    __hip_bfloat16* big = h + M * Cn;       // M*1536 bf16: q,k,v fragment-packed; then y1 packed
    __hip_bfloat16* o   = big + M * FFn;    // M*384 bf16 attention output, packed-A
    __hip_bfloat16* pQKV = o + M * Cn;      // 384*1152 B-packed
    __hip_bfloat16* pWp  = pQKV + Cn * 1152;
    __hip_bfloat16* pW1  = pWp + Cn * Cn;
    __hip_bfloat16* pW2  = pW1 + Cn * FFn;

    float* x2 = (float*)d_out;

    pack_qkv_kernel<<<(Cn * 1152 + 255) / 256, 256, 0, stream>>>(Wq, Wk, Wv, pQKV);
    pack_b_kernel<<<(Cn * Cn + 255) / 256, 256, 0, stream>>>(Wp, pWp, Cn, Cn);
    pack_b_kernel<<<(Cn * FFn + 255) / 256, 256, 0, stream>>>(W1, pW1, Cn, FFn);
    pack_b_kernel<<<(FFn * Cn + 255) / 256, 256, 0, stream>>>(W2, pW2, FFn, Cn);

    // 1) h = LN1(x), packed-A
    ln_pack_kernel<<<M / 16, 256, 0, stream>>>(x, g1, be1, h);
    // 2) qkv  (GX=18 -> 2304 blocks); q,k,v all fragment-packed; persistent-B
    gemm_persist<1152, 0><<<2304, 256, 0, stream>>>(h, pQKV, nullptr, nullptr, nullptr, big);
    // 3) attention: 4 blocks per (b,h), one q-tile per wave, K in LDS; O packed-A
    attn_mfma_kernel<<<Bn * Hn * 4, 256, 0, stream>>>(big, big + SECn, big + 2 * SECn, o);
    // 4) x2 = x + o@Wp + bp   (GX=6 -> 768 blocks), fp32 row-major; persistent-B
    gemm_persist<Cn, 1><<<768, 256, 0, stream>>>(o, pWp, bp, x, x2, nullptr);
    // 5) h2 = LN2(x2), packed-A
    ln_pack_kernel<<<M / 16, 256, 0, stream>>>(x2, g2, be2, h);
    // 6) y1 = relu(h2 @ W1 + b1)  (GX=24 -> 3072 blocks), packed-A output; persistent-B
    gemm_persist<FFn, 2><<<3072, 256, 0, stream>>>(h, pW1, b1, nullptr, nullptr, big);
    // 7) out = x2 + y1 @ W2 + b2  (GX=6 -> 768 blocks), fp32 row-major; chunked pipeline
    gemm_mfma<FFn, Cn, 1><<<768, 256, 0, stream>>>(big, pW2, b2, x2, x2, nullptr);
}

// Round 10
// 235.076 us; speedup vs baseline: 1.0510x; 1.0510x over previous
//
#include <hip/hip_runtime.h>
#include <hip/hip_bf16.h>
#include <math.h>

#define Bn 64
#define Tn 256
#define Cn 384
#define Hn 6
#define HSn 64
#define FFn 1536
#define EPSn 1e-3f
#define SECn 6291456  // B*H*T*HS = one q/k/v section, elements

typedef __attribute__((ext_vector_type(4))) float f32x4;
typedef __attribute__((ext_vector_type(2))) float f32x2;
typedef __attribute__((ext_vector_type(8))) short short8;
typedef __attribute__((ext_vector_type(4))) short short4v;
typedef __attribute__((ext_vector_type(2))) short short2v;

__device__ __forceinline__ void async_copy16(void* lds, const void* g) {
    __builtin_amdgcn_global_load_lds(
        (const __attribute__((address_space(1))) void*)g,
        (__attribute__((address_space(3))) void*)lds, 16, 0, 0);
}

__device__ __forceinline__ short f2bf(float v) {
    __hip_bfloat16 h = __float2bfloat16(v);
    return *(short*)&h;
}

// Packed-A layout for [M x K] bf16: fragment block (mt, kc) of 1 KB:
//   addr = ((mt * (K/32) + kc) * 512) + lane*8 + j
//   value = A[mt*16 + (lane&15)][kc*32 + (lane>>4)*8 + j]

// ---------------- LayerNorm -> packed-A bf16 (block = 16 rows = one m-tile) ----------------
__global__ __launch_bounds__(256) void ln_pack_kernel(const float* __restrict__ x,
                                                      const float* __restrict__ g,
                                                      const float* __restrict__ be,
                                                      __hip_bfloat16* __restrict__ outPk) {
    int mt = blockIdx.x;
    int tid = threadIdx.x;
    int lane = tid & 63, wave = tid >> 6;
    __shared__ short rows[16 * 392];  // stride 392 shorts (784 B, 16B-aligned per row)
#pragma unroll
    for (int i = 0; i < 4; i++) {
        int r = wave * 4 + i;
        const float* xr = x + ((size_t)mt * 16 + r) * Cn;
        f32x4 a = *(const f32x4*)(xr + lane * 4);
        f32x2 b = *(const f32x2*)(xr + 256 + lane * 2);
        float s = a.x + a.y + a.z + a.w + b.x + b.y;
#pragma unroll
        for (int off = 32; off; off >>= 1) s += __shfl_xor(s, off);
        float mu = s * (1.0f / Cn);
        f32x4 da = a - mu;
        f32x2 db = b - mu;
        float sq = da.x * da.x + da.y * da.y + da.z * da.z + da.w * da.w + db.x * db.x + db.y * db.y;
#pragma unroll
        for (int off = 32; off; off >>= 1) sq += __shfl_xor(sq, off);
        float rs = rsqrtf(sq * (1.0f / Cn) + EPSn);
        f32x4 g4 = *(const f32x4*)(g + lane * 4);
        f32x2 g2 = *(const f32x2*)(g + 256 + lane * 2);
        f32x4 e4 = *(const f32x4*)(be + lane * 4);
        f32x2 e2 = *(const f32x2*)(be + 256 + lane * 2);
        f32x4 y4 = da * rs * g4 + e4;
        f32x2 y2 = db * rs * g2 + e2;
        short4v o4 = {f2bf(y4.x), f2bf(y4.y), f2bf(y4.z), f2bf(y4.w)};
        *(short4v*)(&rows[r * 392 + lane * 4]) = o4;
        short2v o2 = {f2bf(y2.x), f2bf(y2.y)};
        *(short2v*)(&rows[r * 392 + 256 + lane * 2]) = o2;
    }
    __syncthreads();
    int r = lane & 15, q = lane >> 4;
#pragma unroll
    for (int p = 0; p < 3; p++) {
        int f = p * 4 + (tid >> 6);  // fragment (k-chunk) 0..11
        short8 v = *(const short8*)(&rows[r * 392 + f * 32 + q * 8]);
        *(short8*)((short*)outPk + ((size_t)mt * 12 + f) * 512 + lane * 8) = v;
    }
}

// ---------------- Fused weight packing: all 4 weight tensors in ONE launch ----------------
__device__ __forceinline__ void pack_b_one(const float* __restrict__ W,
                                           __hip_bfloat16* __restrict__ out, int N, int id) {
    int tile = id >> 9, lane = (id >> 3) & 63, j = id & 7;
    int ntiles = N >> 4;
    int k = (tile / ntiles) * 32 + ((lane >> 4) << 3) + j;
    int n = (tile % ntiles) * 16 + (lane & 15);
    out[id] = __float2bfloat16(W[(size_t)k * N + n]);
}

#define QKV_E 442368   // 384*1152
#define WP_E  147456   // 384*384
#define W1_E  589824   // 384*1536
#define W2_E  589824   // 1536*384

__global__ __launch_bounds__(256) void pack_all_kernel(
    const float* __restrict__ Wq, const float* __restrict__ Wk, const float* __restrict__ Wv,
    const float* __restrict__ Wp, const float* __restrict__ W1, const float* __restrict__ W2,
    __hip_bfloat16* __restrict__ pQKV, __hip_bfloat16* __restrict__ pWp,
    __hip_bfloat16* __restrict__ pW1, __hip_bfloat16* __restrict__ pW2) {
    int id = blockIdx.x * 256 + threadIdx.x;
    if (id < QKV_E) {
        // fused [Wq|Wk|Wv] -> B [K=384, N=1152]
        int tile = id >> 9, lane = (id >> 3) & 63, j = id & 7;
        int k = (tile / 72) * 32 + ((lane >> 4) << 3) + j;
        int n = (tile % 72) * 16 + (lane & 15);
        int sec = n / Cn, rem = n % Cn;
        int hh = rem >> 6, d = rem & 63;
        const float* W = (sec == 0) ? Wq : ((sec == 1) ? Wk : Wv);
        pQKV[id] = __float2bfloat16(W[((size_t)hh * Cn + k) * HSn + d]);
    } else if (id < QKV_E + WP_E) {
        pack_b_one(Wp, pWp, Cn, id - QKV_E);
    } else if (id < QKV_E + WP_E + W1_E) {
        pack_b_one(W1, pW1, FFn, id - (QKV_E + WP_E));
    } else {
        pack_b_one(W2, pW2, Cn, id - (QKV_E + WP_E + W1_E));
    }
}

// ---------------- Persistent-B MFMA GEMM for K=384: whole B panel in LDS ----------------
// Block tile 128(M) x 64(N). The ENTIRE B panel for this colblk (K=384 x 64 = 48 KB,
// 48 fragment tiles) is staged ONCE into LDS via global_load_lds; one barrier; then a
// fully barrier-free K-loop: A fragment-direct from global in 4 quarter-K register
// double-buffers (static indices), B via conflict-free ds_read_b128 (lane*16B).
// Epilogue reuses the then-dead B panel as transpose strips (one barrier).
// LDS = 48 KB -> 3 blocks/CU.
template <int NN, int EPI>
__global__ __launch_bounds__(256, 3) void gemm_persist(const __hip_bfloat16* __restrict__ Apk,
                                                       const __hip_bfloat16* __restrict__ Bp,
                                                       const float* __restrict__ bias,
                                                       const float* __restrict__ resid,
                                                       float* __restrict__ outF,
                                                       __hip_bfloat16* __restrict__ outB) {
    constexpr int GX = NN / 64;
    constexpr int K32 = 12;  // K = 384
    constexpr int NT16 = NN / 16;
    __shared__ __align__(16) short ldsB[48 * 512];  // 48 KB: full B panel; then epi strips

    int l = blockIdx.x;
    int xcd = l & 7, i = l >> 3;
    int rowblk = xcd * 16 + i / GX;
    int colblk = i - (i / GX) * GX;

    int lane = threadIdx.x & 63, wave = threadIdx.x >> 6;
    int lrow = lane & 15, lquad = lane >> 4;
    int m0 = rowblk * 128;
    int n0 = colblk * 64;
    int mt0 = (m0 >> 4) + wave * 2;  // wave's two m-tiles: mt0, mt0+1

    // stage full B panel: 48 tiles of 1 KB, 12 per wave
    {
        const short* bbase = (const short*)Bp + (size_t)(n0 >> 4) * 512 + lane * 8;
#pragma unroll
        for (int t = 0; t < 12; t++) {
            int idx = wave * 12 + t;       // tile index = kf*4 + ntl
            int kf = idx >> 2, ntl = idx & 3;
            async_copy16(&ldsB[idx * 512], bbase + ((size_t)kf * NT16 + ntl) * 512);
        }
    }

    f32x4 acc[2][4];
#pragma unroll
    for (int st = 0; st < 2; st++)
#pragma unroll
        for (int nt = 0; nt < 4; nt++) acc[st][nt] = (f32x4){0.f, 0.f, 0.f, 0.f};

    const short* a0p = (const short*)Apk + ((size_t)mt0 * K32) * 512 + lane * 8;
    const short* a1p = a0p + (size_t)K32 * 512;

    // A quarter-K register double buffer: 3 kf per quarter, 4 quarters
    short8 af[2][2][3];
#pragma unroll
    for (int kf = 0; kf < 3; kf++) {
        af[0][0][kf] = *(const short8*)(a0p + kf * 512);
        af[0][1][kf] = *(const short8*)(a1p + kf * 512);
    }
    __syncthreads();  // B panel ready

#pragma unroll
    for (int q = 0; q < 4; q++) {
        if (q < 3) {
#pragma unroll
            for (int kf = 0; kf < 3; kf++) {
                af[(q + 1) & 1][0][kf] = *(const short8*)(a0p + ((q + 1) * 3 + kf) * 512);
                af[(q + 1) & 1][1][kf] = *(const short8*)(a1p + ((q + 1) * 3 + kf) * 512);
            }
        }
#pragma unroll
        for (int kf = 0; kf < 3; kf++) {
            int kfa = q * 3 + kf;
#pragma unroll
            for (int nt = 0; nt < 4; nt++) {
                short8 bf = *(const short8*)(&ldsB[(kfa * 4 + nt) * 512 + lane * 8]);
                acc[0][nt] = __builtin_amdgcn_mfma_f32_16x16x32_bf16(af[q & 1][0][kf], bf,
                                                                     acc[0][nt], 0, 0, 0);
                acc[1][nt] = __builtin_amdgcn_mfma_f32_16x16x32_bf16(af[q & 1][1][kf], bf,
                                                                     acc[1][nt], 0, 0, 0);
            }
        }
    }
    __syncthreads();  // B panel dead -> reuse as epilogue strips

    if (EPI == 1) {
        // fp32 out = resid + acc + bias (row-major), strip-by-strip (16 x 64 fp32, stride 76)
        float* twf = (float*)((char*)ldsB + wave * 4864);
        float bnv[4];
#pragma unroll
        for (int nt = 0; nt < 4; nt++) bnv[nt] = bias[n0 + nt * 16 + lrow];
#pragma unroll
        for (int st = 0; st < 2; st++) {
            int mbase = m0 + (2 * wave + st) * 16;
#pragma unroll
            for (int nt = 0; nt < 4; nt++)
#pragma unroll
                for (int r = 0; r < 4; r++)
                    twf[(lquad * 4 + r) * 76 + nt * 16 + lrow] = acc[st][nt][r] + bnv[nt];
            int row = lane >> 2, seg = lane & 3;
            int m = mbase + row;
            const float* rrow = resid + (size_t)m * NN + n0 + seg * 16;
            float* orow = outF + (size_t)m * NN + n0 + seg * 16;
#pragma unroll
            for (int c = 0; c < 4; c++) {
                f32x4 vv = *(const f32x4*)(&twf[row * 76 + seg * 16 + c * 4]);
                f32x4 rv = *(const f32x4*)(rrow + c * 4);
                *(f32x4*)(orow + c * 4) = vv + rv;
            }
            __builtin_amdgcn_s_waitcnt(0);  // wave-local strip reuse
        }
    } else {
        // bf16 cases: full 32 rows x 64 cols per-wave strip (stride 72 shorts, 16B-aligned rows)
        short* tws = (short*)((char*)ldsB + wave * 4864);
        float bnv[4];
        if (EPI == 2) {
#pragma unroll
            for (int nt = 0; nt < 4; nt++) bnv[nt] = bias[n0 + nt * 16 + lrow];
        }
#pragma unroll
        for (int st = 0; st < 2; st++)
#pragma unroll
            for (int nt = 0; nt < 4; nt++)
#pragma unroll
                for (int r = 0; r < 4; r++) {
                    float v = acc[st][nt][r];
                    if (EPI == 2) v = fmaxf(v + bnv[nt], 0.0f);
                    tws[(st * 16 + lquad * 4 + r) * 72 + nt * 16 + lrow] = f2bf(v);
                }
        if (EPI == 2) {
            // y1 -> packed-A layout for FF2 (K_ff2 = NN, so K32_out = NN/32)
#pragma unroll
            for (int st2 = 0; st2 < 2; st2++) {
                int mt = (m0 >> 4) + wave * 2 + st2;
#pragma unroll
                for (int kcl = 0; kcl < 2; kcl++) {
                    int kc = (n0 >> 5) + kcl;
                    short8 v = *(const short8*)(
                        &tws[(st2 * 16 + (lane & 15)) * 72 + kcl * 32 + (lane >> 4) * 8]);
                    *(short8*)((short*)outB + ((size_t)mt * (NN / 32) + kc) * 512 + lane * 8) = v;
                }
            }
        } else {
            // EPI 0 (qkv): q -> packed-A frag tiles, k -> packed-B frag tiles (same mapping),
            // v -> packed-B frag tiles for PV. All fragment-direct, no row-major scatter.
            int sec = n0 / 384;
            int rem0 = n0 - sec * 384;
            int hh = rem0 >> 6;  // wave-uniform
            int b = m0 >> 8;
            int t_base = (m0 & 255) + wave * 32;
            int bh2 = b * Hn + hh;
            if (sec < 2) {
                // tile index (t/16)*2 + (d/32); value = X[t = st*16 + (lane&15)][d = kc*32 + quad*8 + j]
                short* outp = (short*)outB + (size_t)sec * SECn + (size_t)bh2 * 16384 +
                              (size_t)(t_base >> 4) * 1024 + lane * 8;
#pragma unroll
                for (int st2 = 0; st2 < 2; st2++)
#pragma unroll
                    for (int kc = 0; kc < 2; kc++) {
                        short8 v8 = *(const short8*)(
                            &tws[(st2 * 16 + (lane & 15)) * 72 + kc * 32 + (lane >> 4) * 8]);
                        *(short8*)(outp + (st2 * 2 + kc) * 512) = v8;
                    }
            } else {
                short* vout = (short*)outB + (size_t)2 * SECn + (size_t)bh2 * 16384 +
                              (size_t)((t_base >> 5) * 4) * 512;
#pragma unroll
                for (int dt = 0; dt < 4; dt++) {
                    short8 v8;
#pragma unroll
                    for (int j = 0; j < 8; j++) {
                        int t_loc = ((lane >> 4) << 3) + j;
                        v8[j] = tws[t_loc * 72 + dt * 16 + (lane & 15)];
                    }
                    *(short8*)(vout + dt * 512 + lane * 8) = v8;
                }
            }
        }
    }
}

// ---------------- Pipelined MFMA GEMM (K=1536 / FF2): LDS-shared B, chunked ----------------
template <int KK, int NN, int EPI>
__global__ __launch_bounds__(256) void gemm_mfma(const __hip_bfloat16* __restrict__ Apk,
                                                 const __hip_bfloat16* __restrict__ Bp,
                                                 const float* __restrict__ bias,
                                                 const float* __restrict__ resid,
                                                 float* __restrict__ outF,
                                                 __hip_bfloat16* __restrict__ outB) {
    constexpr int GX = NN / 64;
    constexpr int K32 = KK / 32;
    constexpr int NC = K32 / 4;   // number of 128-deep K chunks
    constexpr int NT16 = NN / 16;
    __shared__ __align__(16) short ldsB[2 * 8192];  // 32 KB: B chunk double buffer (+ epi strips)

    int l = blockIdx.x;
    int xcd = l & 7, i = l >> 3;
    int rowblk = xcd * 16 + i / GX;
    int colblk = i - (i / GX) * GX;

    int lane = threadIdx.x & 63, wave = threadIdx.x >> 6;
    int lrow = lane & 15, lquad = lane >> 4;
    int m0 = rowblk * 128;
    int n0 = colblk * 64;
    int mt0 = (m0 >> 4) + wave * 2;  // wave's two m-tiles: mt0, mt0+1

    f32x4 acc[2][4];
#pragma unroll
    for (int st = 0; st < 2; st++)
#pragma unroll
        for (int nt = 0; nt < 4; nt++) acc[st][nt] = (f32x4){0.f, 0.f, 0.f, 0.f};

    const short* a0p = (const short*)Apk + ((size_t)mt0 * K32) * 512 + lane * 8;
    const short* a1p = a0p + (size_t)K32 * 512;
    // B source for this wave's staged k-frag (kf == wave) of chunk 0:
    const short* bsrc = (const short*)Bp + ((size_t)wave * NT16 + (n0 >> 4)) * 512 + lane * 8;
    short* bdst0 = ldsB + wave * 2048;  // frags [kf=wave][nt 0..3]

    // prologue: stage chunk 0, load A chunk 0
#pragma unroll
    for (int nt = 0; nt < 4; nt++) async_copy16(bdst0 + nt * 512, bsrc + nt * 512);
    short8 aR[2][2][4];
#pragma unroll
    for (int kf = 0; kf < 4; kf++) {
        aR[0][0][kf] = *(const short8*)(a0p + kf * 512);
        aR[0][1][kf] = *(const short8*)(a1p + kf * 512);
    }

#pragma unroll
    for (int c = 0; c < NC; c++) {
        __syncthreads();  // B(c) ready (stage issued one full chunk ago)
        if (c + 1 < NC) {
            const short* bs = bsrc + (size_t)(c + 1) * 4 * NT16 * 512;
            short* bd = ldsB + ((c + 1) & 1) * 8192 + wave * 2048;
#pragma unroll
            for (int nt = 0; nt < 4; nt++) async_copy16(bd + nt * 512, bs + nt * 512);
#pragma unroll
            for (int kf = 0; kf < 4; kf++) {
                aR[(c + 1) & 1][0][kf] = *(const short8*)(a0p + ((c + 1) * 4 + kf) * 512);
                aR[(c + 1) & 1][1][kf] = *(const short8*)(a1p + ((c + 1) * 4 + kf) * 512);
            }
        }
        const short* bl = ldsB + (c & 1) * 8192 + lane * 8;
#pragma unroll
        for (int kf = 0; kf < 4; kf++) {
#pragma unroll
            for (int nt = 0; nt < 4; nt++) {
                short8 bf = *(const short8*)(bl + (kf * 4 + nt) * 512);
                acc[0][nt] = __builtin_amdgcn_mfma_f32_16x16x32_bf16(aR[c & 1][0][kf], bf,
                                                                     acc[0][nt], 0, 0, 0);
                acc[1][nt] = __builtin_amdgcn_mfma_f32_16x16x32_bf16(aR[c & 1][1][kf], bf,
                                                                     acc[1][nt], 0, 0, 0);
            }
        }
    }
    __syncthreads();  // before reusing ldsB as epilogue strips

    if (EPI == 1) {
        // fp32 out = resid + acc + bias (row-major), strip-by-strip (16 x 64 fp32, stride 76)
        float* twf = (float*)((char*)ldsB + wave * 4864);
        float bnv[4];
#pragma unroll
        for (int nt = 0; nt < 4; nt++) bnv[nt] = bias[n0 + nt * 16 + lrow];
#pragma unroll
        for (int st = 0; st < 2; st++) {
            int mbase = m0 + (2 * wave + st) * 16;
#pragma unroll
            for (int nt = 0; nt < 4; nt++)
#pragma unroll
                for (int r = 0; r < 4; r++)
                    twf[(lquad * 4 + r) * 76 + nt * 16 + lrow] = acc[st][nt][r] + bnv[nt];
            int row = lane >> 2, seg = lane & 3;
            int m = mbase + row;
            const float* rrow = resid + (size_t)m * NN + n0 + seg * 16;
            float* orow = outF + (size_t)m * NN + n0 + seg * 16;
#pragma unroll
            for (int c = 0; c < 4; c++) {
                f32x4 vv = *(const f32x4*)(&twf[row * 76 + seg * 16 + c * 4]);
                f32x4 rv = *(const f32x4*)(rrow + c * 4);
                *(f32x4*)(orow + c * 4) = vv + rv;
            }
            __builtin_amdgcn_s_waitcnt(0);  // wave-local strip reuse
        }
    } else {
        // bf16 cases (unused for FF2 but kept for completeness)
        short* tws = (short*)((char*)ldsB + wave * 4864);
        float bnv[4];
        if (EPI == 2) {
#pragma unroll
            for (int nt = 0; nt < 4; nt++) bnv[nt] = bias[n0 + nt * 16 + lrow];
        }
#pragma unroll
        for (int st = 0; st < 2; st++)
#pragma unroll
            for (int nt = 0; nt < 4; nt++)
#pragma unroll
                for (int r = 0; r < 4; r++) {
                    float v = acc[st][nt][r];
                    if (EPI == 2) v = fmaxf(v + bnv[nt], 0.0f);
                    tws[(st * 16 + lquad * 4 + r) * 72 + nt * 16 + lrow] = f2bf(v);
                }
        if (EPI == 2) {
#pragma unroll
            for (int st2 = 0; st2 < 2; st2++) {
                int mt = (m0 >> 4) + wave * 2 + st2;
#pragma unroll
                for (int kcl = 0; kcl < 2; kcl++) {
                    int kc = (n0 >> 5) + kcl;
                    short8 v = *(const short8*)(
                        &tws[(st2 * 16 + (lane & 15)) * 72 + kcl * 32 + (lane >> 4) * 8]);
                    *(short8*)((short*)outB + ((size_t)mt * (NN / 32) + kc) * 512 + lane * 8) = v;
                }
            }
        }
    }
}

// ---------------- Flash-style MFMA attention: balanced blocks, K staged in LDS ----------------
// Grid = B*H*4. Block group jgr owns CONSECUTIVE q-tiles {4*jgr .. 4*jgr+3} (one per wave).
// Previous mapping put one heavy (qt>=12) wave in EVERY block -> every block ran at
// worst-case duration. Now block cost is proportional to jgr (~2:6:10:14) and heavy
// groups are dispatched FIRST (longest-job-first) so light blocks backfill the CUs.
// Light blocks also stage only the K tiles they can see (4*jgr+4 of 16 "super" tiles).
__global__ __launch_bounds__(256) void attn_mfma_kernel(const __hip_bfloat16* __restrict__ qp,
                                                        const __hip_bfloat16* __restrict__ kp,
                                                        const __hip_bfloat16* __restrict__ vp,
                                                        __hip_bfloat16* __restrict__ o) {
    __shared__ short Kl[16 * 1024];  // 32 KB: K fragment tiles, linear copy of kp section
    __shared__ short Pl[4 * 2048];   // 16 KB: per-wave P half-buffer (4 tiles) / epi strip
    int blk = blockIdx.x;
    int bh = blk % (Bn * Hn);  // same-bh blocks land on the same XCD (384 % 8 == 0)
    int jgr = 3 - blk / (Bn * Hn);  // heavy q-tile groups dispatch first
    int b = bh / Hn, hh = bh - b * Hn;
    int tid = threadIdx.x;
    int lane = tid & 63, wave = tid >> 6;
    int c16 = lane & 15, quad = lane >> 4;
    int qt = (jgr << 2) + wave;  // block owns qt {4*jgr .. 4*jgr+3}

    const short* ks = (const short*)kp + (size_t)bh * 16384;
    // stage K super-tiles 0 .. 4*jgr+3 (1 KB each): jgr+1 async copies per wave
    int per = jgr + 1;
#pragma unroll
    for (int i = 0; i < 4; i++) {
        if (i < per) {
            int tile = wave * per + i;
            async_copy16(&Kl[tile * 1024], ks + tile * 1024 + lane * 8);
            async_copy16(&Kl[tile * 1024 + 512], ks + tile * 1024 + 512 + lane * 8);
        }
    }

    const short* qs = (const short*)qp + (size_t)bh * 16384 + (size_t)qt * 1024 + lane * 8;
    const short* vs = (const short*)vp + (size_t)bh * 16384 + lane * 8;
    short* Pw = Pl + wave * 2048;

    short8 aq0 = *(const short8*)(qs);
    short8 aq1 = *(const short8*)(qs + 512);

    int st_max = qt;
    int kb_count = (qt + 2) >> 1;
    int covered = kb_count * 2;
    int qrow0 = qt * 16;

    __syncthreads();  // K staged (compiler drains vmcnt before s_barrier)

    f32x4 accS[16];
#pragma unroll
    for (int st = 0; st < 16; st++) accS[st] = (f32x4){0.f, 0.f, 0.f, 0.f};
#pragma unroll
    for (int st = 0; st < 16; st++) {
        if (st <= st_max) {
            short8 bk0 = *(const short8*)(&Kl[st * 1024 + lane * 8]);
            short8 bk1 = *(const short8*)(&Kl[st * 1024 + 512 + lane * 8]);
            accS[st] = __builtin_amdgcn_mfma_f32_16x16x32_bf16(aq0, bk0, accS[st], 0, 0, 0);
            accS[st] = __builtin_amdgcn_mfma_f32_16x16x32_bf16(aq1, bk1, accS[st], 0, 0, 0);
        }
    }

    // pass 1: causal mask + scale + row max
    float mx[4];
#pragma unroll
    for (int r = 0; r < 4; r++) {
        int row = qrow0 + quad * 4 + r;
        float m = -INFINITY;
#pragma unroll
        for (int st = 0; st < 16; st++) {
            if (st <= st_max) {
                int col = st * 16 + c16;
                float a = (col <= row) ? accS[st][r] * 0.125f : -INFINITY;
                accS[st][r] = a;
                m = fmaxf(m, a);
            }
        }
#pragma unroll
        for (int off = 8; off; off >>= 1) m = fmaxf(m, __shfl_xor(m, off));
        mx[r] = m;
    }

    // pass 2: exp + P store + PV, in two 4-kbi halves (P half-buffer reuse)
    float sum[4] = {0.f, 0.f, 0.f, 0.f};
    f32x4 accO[4];
#pragma unroll
    for (int nt = 0; nt < 4; nt++) accO[nt] = (f32x4){0.f, 0.f, 0.f, 0.f};
#pragma unroll
    for (int half = 0; half < 2; half++) {
        int st_lo = half * 8;
        if (st_lo < covered) {
#pragma unroll
            for (int st2 = 0; st2 < 8; st2++) {
                int st = st_lo + st2;
                if (st < covered) {
#pragma unroll
                    for (int r = 0; r < 4; r++) {
                        float e = 0.0f;
                        if (st <= st_max) {
                            e = __expf(accS[st][r] - mx[r]);
                            sum[r] += e;
                        }
                        int cl = st2 * 16 + c16;
                        Pw[(cl >> 5) * 512 + (((cl >> 3) & 3) * 16 + quad * 4 + r) * 8 +
                           (cl & 7)] = f2bf(e);
                    }
                }
            }
#pragma unroll
            for (int k2 = 0; k2 < 4; k2++) {
                int kbi = half * 4 + k2;
                if (kbi < kb_count) {
                    short8 ap = *(const short8*)(Pw + k2 * 512 + lane * 8);
#pragma unroll
                    for (int nt = 0; nt < 4; nt++) {
                        short8 bv = *(const short8*)(vs + (kbi * 4 + nt) * 512);
                        accO[nt] = __builtin_amdgcn_mfma_f32_16x16x32_bf16(ap, bv, accO[nt],
                                                                           0, 0, 0);
                    }
                }
            }
        }
    }

    float inv[4];
#pragma unroll
    for (int r = 0; r < 4; r++) {
        float s = sum[r];
#pragma unroll
        for (int off = 8; off; off >>= 1) s += __shfl_xor(s, off);
        inv[r] = 1.0f / s;
    }

    // ---- O epilogue: C-layout -> strip (stride 72) -> packed-A global ----
#pragma unroll
    for (int nt = 0; nt < 4; nt++)
#pragma unroll
        for (int r = 0; r < 4; r++)
            Pw[(quad * 4 + r) * 72 + nt * 16 + c16] = f2bf(accO[nt][r] * inv[r]);
    int mt = (b << 4) + qt;  // (b*256 + qt*16) / 16
#pragma unroll
    for (int kcl = 0; kcl < 2; kcl++) {
        short8 v = *(const short8*)(&Pw[(lane & 15) * 72 + kcl * 32 + (lane >> 4) * 8]);
        *(short8*)((short*)o + ((size_t)mt * 12 + hh * 2 + kcl) * 512 + lane * 8) = v;
    }
}

extern "C" void kernel_launch(void* const* d_in, const int* in_sizes, int n_in,
                              void* d_out, int out_size, void* d_ws, size_t ws_size,
                              hipStream_t stream) {
    const float* x  = (const float*)d_in[0];
    const float* Wq = (const float*)d_in[1];
    const float* Wk = (const float*)d_in[2];
    const float* Wv = (const float*)d_in[3];
    const float* Wp = (const float*)d_in[4];
    const float* bp = (const float*)d_in[5];
    const float* W1 = (const float*)d_in[6];
    const float* b1 = (const float*)d_in[7];
    const float* W2 = (const float*)d_in[8];
    const float* b2 = (const float*)d_in[9];
    const float* g1 = (const float*)d_in[10];
    const float* be1 = (const float*)d_in[11];
    const float* g2 = (const float*)d_in[12];
    const float* be2 = (const float*)d_in[13];

    const size_t M = (size_t)Bn * Tn;  // 16384
    __hip_bfloat16* ws  = (__hip_bfloat16*)d_ws;
    __hip_bfloat16* h   = ws;               // M*384 bf16 packed-A (LN1 out; reused as h2)
    __hip_bfloat16* big = h + M * Cn;       // M*1536 bf16: q,k,v fragment-packed; then y1 packed
    __hip_bfloat16* o   = big + M * FFn;    // M*384 bf16 attention output, packed-A
    __hip_bfloat16* pQKV = o + M * Cn;      // 384*1152 B-packed
    __hip_bfloat16* pWp  = pQKV + Cn * 1152;
    __hip_bfloat16* pW1  = pWp + Cn * Cn;
    __hip_bfloat16* pW2  = pW1 + Cn * FFn;

    float* x2 = (float*)d_out;

    // 0) pack all weights in ONE launch (was 4 launches)
    pack_all_kernel<<<(QKV_E + WP_E + W1_E + W2_E) / 256, 256, 0, stream>>>(
        Wq, Wk, Wv, Wp, W1, W2, pQKV, pWp, pW1, pW2);

    // 1) h = LN1(x), packed-A
    ln_pack_kernel<<<M / 16, 256, 0, stream>>>(x, g1, be1, h);
    // 2) qkv  (GX=18 -> 2304 blocks); q,k,v all fragment-packed; persistent-B
    gemm_persist<1152, 0><<<2304, 256, 0, stream>>>(h, pQKV, nullptr, nullptr, nullptr, big);
    // 3) attention: 4 balanced blocks per (b,h), heavy-first; O packed-A
    attn_mfma_kernel<<<Bn * Hn * 4, 256, 0, stream>>>(big, big + SECn, big + 2 * SECn, o);
    // 4) x2 = x + o@Wp + bp   (GX=6 -> 768 blocks), fp32 row-major; persistent-B
    gemm_persist<Cn, 1><<<768, 256, 0, stream>>>(o, pWp, bp, x, x2, nullptr);
    // 5) h2 = LN2(x2), packed-A
    ln_pack_kernel<<<M / 16, 256, 0, stream>>>(x2, g2, be2, h);
    // 6) y1 = relu(h2 @ W1 + b1)  (GX=24 -> 3072 blocks), packed-A output; persistent-B
    gemm_persist<FFn, 2><<<3072, 256, 0, stream>>>(h, pW1, b1, nullptr, nullptr, big);
    // 7) out = x2 + y1 @ W2 + b2  (GX=6 -> 768 blocks), fp32 row-major; chunked pipeline
    gemm_mfma<FFn, Cn, 1><<<768, 256, 0, stream>>>(big, pW2, b2, x2, x2, nullptr);
}